// Round 4
// baseline (440.448 us; speedup 1.0000x reference)
//
#include <hip/hip_runtime.h>
#include <cmath>

#define BB 2
#define AA 5
#define CH 64
#define HH 128
#define WW 128
#define HW (HH*WW)
#define NIMG (BB*AA)

typedef __attribute__((ext_vector_type(8))) _Float16 half8;
typedef __attribute__((ext_vector_type(4))) float floatx4;

__device__ inline half8 hzero() {
    half8 v;
#pragma unroll
    for (int e = 0; e < 8; ++e) v[e] = (_Float16)0.f;
    return v;
}

// ---------------------------------------------------------------------------
// feats fp32 planar [NIMG,64,H,W] -> NHWC f16 buffer channels 0..63
// ---------------------------------------------------------------------------
__global__ __launch_bounds__(256) void to_nhwc_kernel(
    const float* __restrict__ src, _Float16* __restrict__ dst)
{
    const int img = blockIdx.y;
    const int cg  = blockIdx.x & 7;       // 8 groups of 8 channels
    const int pb  = blockIdx.x >> 3;      // 64 pixel blocks of 256
    const int p   = pb * 256 + threadIdx.x;
    const float* s = src + ((size_t)img * CH + cg * 8) * HW + p;
    half8 v;
#pragma unroll
    for (int e = 0; e < 8; ++e) v[e] = (_Float16)s[e * HW];
    *(half8*)(dst + ((size_t)img * HW + p) * 128 + cg * 8) = v;
}

// ---------------------------------------------------------------------------
// pack wx [192,128,3,3] fp32 -> f16 B-fragment layout:
// wp[cc][tap][gk][oc][e] : k = cc*32 + gk*8 + e, tap = ky*3+kx
// ---------------------------------------------------------------------------
__global__ __launch_bounds__(256) void pack_w_kernel(
    const float* __restrict__ wx, half8* __restrict__ wp)
{
    int idx = blockIdx.x * 256 + threadIdx.x;     // 4*9*4*192 = 27648
    if (idx >= 4 * 9 * 4 * 192) return;
    int oc = idx % 192; int r = idx / 192;
    int gk = r & 3; r >>= 2; int tap = r % 9; int cc = r / 9;
    int ky = tap / 3, kx = tap % 3;
    half8 v;
#pragma unroll
    for (int e = 0; e < 8; ++e)
        v[e] = (_Float16)wx[(((size_t)oc * 128 + cc * 32 + gk * 8 + e) * 3 + ky) * 3 + kx];
    wp[idx] = v;
}

// ---------------------------------------------------------------------------
// fused double-bilinear warp + masked mean; NHWC f16 in (ch 0..63),
// NHWC f16 out (ch 64..127 of the SAME buffer).  (unchanged from R2)
// ---------------------------------------------------------------------------
__global__ __launch_bounds__(256) void warp_mean_kernel(
    const _Float16* __restrict__ nh,     // [NIMG, HW, 128]
    const float* __restrict__ trans,     // [B, A, A, 4, 4]
    _Float16* __restrict__ nhw)          // same buffer
{
    __shared__ float f_lds[16][17][18];

    const int tile = blockIdx.x;
    const int tx0 = (tile & 7) * 16;
    const int ty0 = (tile >> 3) * 16;
    const int c0  = blockIdx.y * 16;
    const int bi  = blockIdx.z;
    const int b   = bi / AA, i = bi % AA;
    const int tid = threadIdx.x;
    const int ltx = tid & 15, lty = tid >> 4;

    float acc[16];
#pragma unroll
    for (int c = 0; c < 16; ++c) acc[c] = 0.f;

    for (int j = 0; j < AA; ++j) {
        if (j == i) continue;
        const float* t = trans + (((size_t)b * AA + i) * AA + j) * 16;
        const float t00 = t[0], t01 = t[1], t03 = t[3];
        const float t10 = t[4], t11 = t[5], t13 = t[7];
        const float dxs = 2.f * t03;
        const float dys = -2.f * t13;
        const float sxf = floorf(dxs), syf = floorf(dys);
        const int sx = (int)sxf, sy = (int)syf;
        const float fx = dxs - sxf, fy = dys - syf;
        const _Float16* srcj = nh + (size_t)(b * AA + j) * HW * 128 + c0;

        for (int idx = tid; idx < 17 * 17; idx += 256) {
            const int lx = idx % 17, ly = idx / 17;
            const int qx = tx0 + sx + lx;
            const int qy = ty0 + sy + ly;
            const bool qin = (qx >= 0) & (qx < WW) & (qy >= 0) & (qy < HH);
            if (!qin) {
#pragma unroll
                for (int c = 0; c < 16; ++c) f_lds[c][ly][lx] = 0.f;
            } else {
                const float xn = (2 * qx + 1) * (1.0f / WW) - 1.f;
                const float yn = (2 * qy + 1) * (1.0f / HH) - 1.f;
                const float sxn = t00 * xn + t01 * yn;
                const float syn = t10 * xn + t11 * yn;
                const float px = 64.f * sxn + 63.5f;
                const float py = 64.f * syn + 63.5f;
                const float x0f = floorf(px), y0f = floorf(py);
                const int x0 = (int)x0f, y0 = (int)y0f;
                const float wx1 = px - x0f, wx0 = 1.f - wx1;
                const float wy1 = py - y0f, wy0 = 1.f - wy1;
                const bool vx0 = (x0 >= 0) & (x0 < WW);
                const bool vx1 = (x0 + 1 >= 0) & (x0 + 1 < WW);
                const bool vy0 = (y0 >= 0) & (y0 < HH);
                const bool vy1 = (y0 + 1 >= 0) & (y0 + 1 < HH);
                const int cx0 = min(max(x0, 0), WW - 1);
                const int cx1 = min(max(x0 + 1, 0), WW - 1);
                const int cy0 = min(max(y0, 0), HH - 1);
                const int cy1 = min(max(y0 + 1, 0), HH - 1);
                const float w00 = (vx0 & vy0) ? wx0 * wy0 : 0.f;
                const float w01 = (vx1 & vy0) ? wx1 * wy0 : 0.f;
                const float w10 = (vx0 & vy1) ? wx0 * wy1 : 0.f;
                const float w11 = (vx1 & vy1) ? wx1 * wy1 : 0.f;
                const size_t o00 = ((size_t)cy0 * WW + cx0) * 128;
                const size_t o01 = ((size_t)cy0 * WW + cx1) * 128;
                const size_t o10 = ((size_t)cy1 * WW + cx0) * 128;
                const size_t o11 = ((size_t)cy1 * WW + cx1) * 128;
                const half8 a0 = *(const half8*)(srcj + o00);
                const half8 a1 = *(const half8*)(srcj + o00 + 8);
                const half8 b0 = *(const half8*)(srcj + o01);
                const half8 b1 = *(const half8*)(srcj + o01 + 8);
                const half8 c0v = *(const half8*)(srcj + o10);
                const half8 c1v = *(const half8*)(srcj + o10 + 8);
                const half8 d0 = *(const half8*)(srcj + o11);
                const half8 d1 = *(const half8*)(srcj + o11 + 8);
#pragma unroll
                for (int c = 0; c < 16; ++c) {
                    const float p00 = (c < 8) ? (float)a0[c & 7] : (float)a1[c & 7];
                    const float p01 = (c < 8) ? (float)b0[c & 7] : (float)b1[c & 7];
                    const float p10 = (c < 8) ? (float)c0v[c & 7] : (float)c1v[c & 7];
                    const float p11 = (c < 8) ? (float)d0[c & 7] : (float)d1[c & 7];
                    f_lds[c][ly][lx] = w00 * p00 + w01 * p01 + w10 * p10 + w11 * p11;
                }
            }
        }
        __syncthreads();

        const float wA = (1.f - fx) * (1.f - fy);
        const float wB = fx * (1.f - fy);
        const float wC = (1.f - fx) * fy;
        const float wD = fx * fy;
#pragma unroll
        for (int c = 0; c < 16; ++c) {
            const float v00 = f_lds[c][lty][ltx];
            const float v01 = f_lds[c][lty][ltx + 1];
            const float v10 = f_lds[c][lty + 1][ltx];
            const float v11 = f_lds[c][lty + 1][ltx + 1];
            acc[c] += wA * v00 + wB * v01 + wC * v10 + wD * v11;
        }
        __syncthreads();
    }

    const float inv = 1.f / (AA - 1);
    _Float16* dst = nhw + ((size_t)bi * HW + (ty0 + lty) * WW + tx0 + ltx) * 128 + 64 + c0;
    half8 o0, o1;
#pragma unroll
    for (int c = 0; c < 8; ++c) { o0[c] = (_Float16)(acc[c] * inv); o1[c] = (_Float16)(acc[c + 8] * inv); }
    *(half8*)dst = o0;
    *(half8*)(dst + 8) = o1;
}

// ---------------------------------------------------------------------------
// MFMA implicit-GEMM 3x3 conv + fused GRU gating.
// v4: BARRIER-FREE K-loop. Full 128-ch input halo tile staged to LDS once
// (one __syncthreads per block). B-fragments loaded per-lane straight from
// the packed weight buffer (L2-resident 442 KB hot set) into registers —
// no LDS for B, no vmcnt(0)+barrier convoy; compiler software-pipelines
// b-loads of step s+1 under the 24 MFMAs of step s.
// ---------------------------------------------------------------------------
__global__ __launch_bounds__(256) void conv_gru_mfma(
    const _Float16* __restrict__ in,    // [NIMG, HW, 128]
    const half8* __restrict__ wp,       // packed weights [36][768]
    const float* __restrict__ bx,       // [192]
    const float* __restrict__ bh,       // [192]
    float* __restrict__ out_f32,        // [NIMG,64,H,W] or null
    _Float16* __restrict__ out_f16)     // [NIMG,HW,128] ch0..63 or null
{
    __shared__ half8 lds_in[16 * 10 * 18];   // [g=16][py=10][px=18], 46080 B

    const int tid = threadIdx.x;
    const int img = blockIdx.z;
    const int x0 = (blockIdx.x & 7) * 16;
    const int y0 = (blockIdx.x >> 3) * 8;
    const int w   = tid >> 6;
    const int ln  = tid & 15;
    const int kq  = (tid & 63) >> 4;
    const int och = w & 1, pxh = w >> 1;

    // ---- stage full 128-ch halo tile (only barrier in the kernel) ----
    const _Float16* inimg = in + (size_t)img * HW * 128;
    for (int f = tid; f < 2880; f += 256) {
        const int g = f / 180; const int r = f % 180;
        const int py = r / 18; const int px = r % 18;
        const int y = y0 + py - 1, x = x0 + px - 1;
        half8 v = hzero();
        if ((unsigned)x < (unsigned)WW && (unsigned)y < (unsigned)HH)
            v = *(const half8*)(inimg + ((size_t)y * WW + x) * 128 + g * 8);
        lds_in[f] = v;
    }

    floatx4 acc[4][6];
#pragma unroll
    for (int s = 0; s < 4; ++s)
#pragma unroll
        for (int t = 0; t < 6; ++t)
#pragma unroll
            for (int r = 0; r < 4; ++r) acc[s][t][r] = 0.f;

    __syncthreads();

    // ---- barrier-free K-loop: 4 ci-chunks x 9 taps ----
    for (int cc = 0; cc < 4; ++cc) {
#pragma unroll
        for (int tap = 0; tap < 9; ++tap) {
            const int dy = tap / 3, dx = tap - dy * 3;
            const half8* wsrc = wp + (size_t)(cc * 9 + tap) * 768
                              + kq * 192 + och * 32 + ln;
            half8 b[6];
#pragma unroll
            for (int t = 0; t < 6; ++t)
                b[t] = wsrc[(t >> 1) * 64 + (t & 1) * 16];
            half8 a[4];
#pragma unroll
            for (int t = 0; t < 4; ++t)
                a[t] = lds_in[((cc * 4 + kq) * 10 + pxh * 4 + t + dy) * 18 + ln + dx];
#pragma unroll
            for (int t = 0; t < 4; ++t)
#pragma unroll
                for (int u = 0; u < 6; ++u)
                    acc[t][u] = __builtin_amdgcn_mfma_f32_16x16x32_f16(a[t], b[u], acc[t][u], 0, 0, 0);
        }
    }

    // epilogue: GRU gating. D layout: col(oc) = ln, row(x) = kq*4+reg.
#pragma unroll
    for (int cp = 0; cp < 2; ++cp) {
        const int c = och * 32 + cp * 16 + ln;          // 0..63
        const float bxr = bx[c] + bh[c];
        const float bxz = bx[64 + c] + bh[64 + c];
        const float bxn = bx[128 + c];
        const float bnn = bh[128 + c];
#pragma unroll
        for (int s = 0; s < 4; ++s) {
            const int y = y0 + pxh * 4 + s;
#pragma unroll
            for (int reg = 0; reg < 4; ++reg) {
                const int x = x0 + kq * 4 + reg;
                const float xr = acc[s][cp][reg] + bxr;
                const float xz = acc[s][2 + cp][reg] + bxz;
                const float xn = acc[s][4 + cp][reg] + bxn;
                const float rg = 1.f / (1.f + __expf(-xr));
                const float zg = 1.f / (1.f + __expf(-xz));
                const float n  = tanhf(xn + rg * bnn);
                const float h  = (1.f - zg) * n;
                if (out_f32)
                    out_f32[((size_t)img * CH + c) * HW + y * WW + x] = h;
                else
                    out_f16[((size_t)img * HW + y * WW + x) * 128 + c] = (_Float16)h;
            }
        }
    }
}

// ---------------------------------------------------------------------------
extern "C" void kernel_launch(void* const* d_in, const int* in_sizes, int n_in,
                              void* d_out, int out_size, void* d_ws, size_t ws_size,
                              hipStream_t stream) {
    const float* feats = (const float*)d_in[0];
    const float* trans = (const float*)d_in[1];
    const float* wx    = (const float*)d_in[2];
    // d_in[3] = wh (unused: h0 = 0)
    const float* bx    = (const float*)d_in[4];
    const float* bh    = (const float*)d_in[5];
    float* out = (float*)d_out;

    char* ws = (char*)d_ws;
    half8*    wpack = (half8*)ws;                              // 442,368 B
    _Float16* B1 = (_Float16*)(ws + 442368);                   // 40 MB NHWC f16
    _Float16* B2 = (_Float16*)(ws + 442368 + (size_t)NIMG * HW * 128 * 2);

    pack_w_kernel<<<108, 256, 0, stream>>>(wx, wpack);
    to_nhwc_kernel<<<dim3(512, NIMG), 256, 0, stream>>>(feats, B1);

    dim3 wgrid(64, 4, NIMG);
    dim3 cgrid(128, 1, NIMG);

    // iteration 1
    warp_mean_kernel<<<wgrid, 256, 0, stream>>>(B1, trans, B1);
    conv_gru_mfma<<<cgrid, 256, 0, stream>>>(B1, wpack, bx, bh, nullptr, B2);
    // iteration 2
    warp_mean_kernel<<<wgrid, 256, 0, stream>>>(B2, trans, B2);
    conv_gru_mfma<<<cgrid, 256, 0, stream>>>(B2, wpack, bx, bh, out, nullptr);
}

// Round 5
// 371.811 us; speedup vs baseline: 1.1846x; 1.1846x over previous
//
#include <hip/hip_runtime.h>
#include <cmath>

#define BB 2
#define AA 5
#define CH 64
#define HH 128
#define WW 128
#define HW (HH*WW)
#define NIMG (BB*AA)

typedef __attribute__((ext_vector_type(8))) _Float16 half8;
typedef __attribute__((ext_vector_type(4))) float floatx4;

__device__ inline half8 hzero() {
    half8 v;
#pragma unroll
    for (int e = 0; e < 8; ++e) v[e] = (_Float16)0.f;
    return v;
}

__device__ inline float fsigmoid(float x) {
    return __builtin_amdgcn_rcpf(1.f + __builtin_amdgcn_exp2f(-1.442695041f * x));
}
__device__ inline float ftanh(float x) {
    return 2.f * fsigmoid(2.f * x) - 1.f;
}

// ---------------------------------------------------------------------------
// feats fp32 planar [NIMG,64,H,W] -> NHWC f16 buffer channels 0..63
// ---------------------------------------------------------------------------
__global__ __launch_bounds__(256) void to_nhwc_kernel(
    const float* __restrict__ src, _Float16* __restrict__ dst)
{
    const int img = blockIdx.y;
    const int cg  = blockIdx.x & 7;       // 8 groups of 8 channels
    const int pb  = blockIdx.x >> 3;      // 64 pixel blocks of 256
    const int p   = pb * 256 + threadIdx.x;
    const float* s = src + ((size_t)img * CH + cg * 8) * HW + p;
    half8 v;
#pragma unroll
    for (int e = 0; e < 8; ++e) v[e] = (_Float16)s[e * HW];
    *(half8*)(dst + ((size_t)img * HW + p) * 128 + cg * 8) = v;
}

// ---------------------------------------------------------------------------
// pack wx [192,128,3,3] fp32 -> f16 B-fragment layout:
// wp[cc][tap][gk][oc][e] : k = cc*32 + gk*8 + e, tap = ky*3+kx
// ---------------------------------------------------------------------------
__global__ __launch_bounds__(256) void pack_w_kernel(
    const float* __restrict__ wx, half8* __restrict__ wp)
{
    int idx = blockIdx.x * 256 + threadIdx.x;     // 4*9*4*192 = 27648
    if (idx >= 4 * 9 * 4 * 192) return;
    int oc = idx % 192; int r = idx / 192;
    int gk = r & 3; r >>= 2; int tap = r % 9; int cc = r / 9;
    int ky = tap / 3, kx = tap % 3;
    half8 v;
#pragma unroll
    for (int e = 0; e < 8; ++e)
        v[e] = (_Float16)wx[(((size_t)oc * 128 + cc * 32 + gk * 8 + e) * 3 + ky) * 3 + kx];
    wp[idx] = v;
}

// ---------------------------------------------------------------------------
// fused double-bilinear warp + masked mean; NHWC f16 in (ch 0..63),
// NHWC f16 out (ch 64..127 of the SAME buffer).  (unchanged from R2)
// ---------------------------------------------------------------------------
__global__ __launch_bounds__(256) void warp_mean_kernel(
    const _Float16* __restrict__ nh,     // [NIMG, HW, 128]
    const float* __restrict__ trans,     // [B, A, A, 4, 4]
    _Float16* __restrict__ nhw)          // same buffer
{
    __shared__ float f_lds[16][17][18];

    const int tile = blockIdx.x;
    const int tx0 = (tile & 7) * 16;
    const int ty0 = (tile >> 3) * 16;
    const int c0  = blockIdx.y * 16;
    const int bi  = blockIdx.z;
    const int b   = bi / AA, i = bi % AA;
    const int tid = threadIdx.x;
    const int ltx = tid & 15, lty = tid >> 4;

    float acc[16];
#pragma unroll
    for (int c = 0; c < 16; ++c) acc[c] = 0.f;

    for (int j = 0; j < AA; ++j) {
        if (j == i) continue;
        const float* t = trans + (((size_t)b * AA + i) * AA + j) * 16;
        const float t00 = t[0], t01 = t[1], t03 = t[3];
        const float t10 = t[4], t11 = t[5], t13 = t[7];
        const float dxs = 2.f * t03;
        const float dys = -2.f * t13;
        const float sxf = floorf(dxs), syf = floorf(dys);
        const int sx = (int)sxf, sy = (int)syf;
        const float fx = dxs - sxf, fy = dys - syf;
        const _Float16* srcj = nh + (size_t)(b * AA + j) * HW * 128 + c0;

        for (int idx = tid; idx < 17 * 17; idx += 256) {
            const int lx = idx % 17, ly = idx / 17;
            const int qx = tx0 + sx + lx;
            const int qy = ty0 + sy + ly;
            const bool qin = (qx >= 0) & (qx < WW) & (qy >= 0) & (qy < HH);
            if (!qin) {
#pragma unroll
                for (int c = 0; c < 16; ++c) f_lds[c][ly][lx] = 0.f;
            } else {
                const float xn = (2 * qx + 1) * (1.0f / WW) - 1.f;
                const float yn = (2 * qy + 1) * (1.0f / HH) - 1.f;
                const float sxn = t00 * xn + t01 * yn;
                const float syn = t10 * xn + t11 * yn;
                const float px = 64.f * sxn + 63.5f;
                const float py = 64.f * syn + 63.5f;
                const float x0f = floorf(px), y0f = floorf(py);
                const int x0 = (int)x0f, y0 = (int)y0f;
                const float wx1 = px - x0f, wx0 = 1.f - wx1;
                const float wy1 = py - y0f, wy0 = 1.f - wy1;
                const bool vx0 = (x0 >= 0) & (x0 < WW);
                const bool vx1 = (x0 + 1 >= 0) & (x0 + 1 < WW);
                const bool vy0 = (y0 >= 0) & (y0 < HH);
                const bool vy1 = (y0 + 1 >= 0) & (y0 + 1 < HH);
                const int cx0 = min(max(x0, 0), WW - 1);
                const int cx1 = min(max(x0 + 1, 0), WW - 1);
                const int cy0 = min(max(y0, 0), HH - 1);
                const int cy1 = min(max(y0 + 1, 0), HH - 1);
                const float w00 = (vx0 & vy0) ? wx0 * wy0 : 0.f;
                const float w01 = (vx1 & vy0) ? wx1 * wy0 : 0.f;
                const float w10 = (vx0 & vy1) ? wx0 * wy1 : 0.f;
                const float w11 = (vx1 & vy1) ? wx1 * wy1 : 0.f;
                const size_t o00 = ((size_t)cy0 * WW + cx0) * 128;
                const size_t o01 = ((size_t)cy0 * WW + cx1) * 128;
                const size_t o10 = ((size_t)cy1 * WW + cx0) * 128;
                const size_t o11 = ((size_t)cy1 * WW + cx1) * 128;
                const half8 a0 = *(const half8*)(srcj + o00);
                const half8 a1 = *(const half8*)(srcj + o00 + 8);
                const half8 b0 = *(const half8*)(srcj + o01);
                const half8 b1 = *(const half8*)(srcj + o01 + 8);
                const half8 c0v = *(const half8*)(srcj + o10);
                const half8 c1v = *(const half8*)(srcj + o10 + 8);
                const half8 d0 = *(const half8*)(srcj + o11);
                const half8 d1 = *(const half8*)(srcj + o11 + 8);
#pragma unroll
                for (int c = 0; c < 16; ++c) {
                    const float p00 = (c < 8) ? (float)a0[c & 7] : (float)a1[c & 7];
                    const float p01 = (c < 8) ? (float)b0[c & 7] : (float)b1[c & 7];
                    const float p10 = (c < 8) ? (float)c0v[c & 7] : (float)c1v[c & 7];
                    const float p11 = (c < 8) ? (float)d0[c & 7] : (float)d1[c & 7];
                    f_lds[c][ly][lx] = w00 * p00 + w01 * p01 + w10 * p10 + w11 * p11;
                }
            }
        }
        __syncthreads();

        const float wA = (1.f - fx) * (1.f - fy);
        const float wB = fx * (1.f - fy);
        const float wC = (1.f - fx) * fy;
        const float wD = fx * fy;
#pragma unroll
        for (int c = 0; c < 16; ++c) {
            const float v00 = f_lds[c][lty][ltx];
            const float v01 = f_lds[c][lty][ltx + 1];
            const float v10 = f_lds[c][lty + 1][ltx];
            const float v11 = f_lds[c][lty + 1][ltx + 1];
            acc[c] += wA * v00 + wB * v01 + wC * v10 + wD * v11;
        }
        __syncthreads();
    }

    const float inv = 1.f / (AA - 1);
    _Float16* dst = nhw + ((size_t)bi * HW + (ty0 + lty) * WW + tx0 + ltx) * 128 + 64 + c0;
    half8 o0, o1;
#pragma unroll
    for (int c = 0; c < 8; ++c) { o0[c] = (_Float16)(acc[c] * inv); o1[c] = (_Float16)(acc[c + 8] * inv); }
    *(half8*)dst = o0;
    *(half8*)(dst + 8) = o1;
}

// ---------------------------------------------------------------------------
// MFMA implicit-GEMM 3x3 conv + fused GRU gating.
// v5: occupancy-first. Block = 64 px (16x4 tile, 27.6 KB halo LDS) x 192 oc.
// Wave w handles c-range [w*16, w*16+16) for ALL 3 gates (12 acc frags =
// 48 VGPR) so GRU gating stays wave-local. Barrier-free K-loop with explicit
// depth-1 register prefetch of b-frags. __launch_bounds__(256,4) pins
// VGPR <= 128 -> 4 blocks/CU, 4 waves/SIMD (2x R4 TLP).
// ---------------------------------------------------------------------------
__global__ __launch_bounds__(256, 4) void conv_gru_mfma(
    const _Float16* __restrict__ in,    // [NIMG, HW, 128]
    const half8* __restrict__ wp,       // packed weights [36][768]
    const float* __restrict__ bx,       // [192]
    const float* __restrict__ bh,       // [192]
    float* __restrict__ out_f32,        // [NIMG,64,H,W] or null
    _Float16* __restrict__ out_f16)     // [NIMG,HW,128] ch0..63 or null
{
    // [g=16][row=6][col=18] half8  (g = channel/8) -> 27648 B
    __shared__ half8 lds_in[16 * 6 * 18];

    const int tid = threadIdx.x;
    const int img = blockIdx.z;
    const int x0 = (blockIdx.x & 7) * 16;       // 8 x-tiles
    const int y0 = (blockIdx.x >> 3) * 4;       // 32 y-tiles
    const int w   = tid >> 6;                   // wave -> c-range w*16..+15
    const int ln  = tid & 15;
    const int kq  = (tid & 63) >> 4;

    // ---- stage 6x18 halo x 128ch (only barrier in the kernel) ----
    const _Float16* inimg = in + (size_t)img * HW * 128;
    for (int f = tid; f < 1728; f += 256) {
        const int g = f / 108; const int r = f % 108;
        const int row = r / 18; const int col = r % 18;
        const int y = y0 + row - 1, x = x0 + col - 1;
        half8 v = hzero();
        if ((unsigned)x < (unsigned)WW && (unsigned)y < (unsigned)HH)
            v = *(const half8*)(inimg + ((size_t)y * WW + x) * 128 + g * 8);
        lds_in[f] = v;
    }

    floatx4 acc[4][3];     // [y-row][gate]
#pragma unroll
    for (int s = 0; s < 4; ++s)
#pragma unroll
        for (int t = 0; t < 3; ++t)
#pragma unroll
            for (int r = 0; r < 4; ++r) acc[s][t][r] = 0.f;

    __syncthreads();

    // ---- barrier-free K-loop: 36 steps (4 ci-chunks x 9 taps) ----
    // b-frag for wave w, gate t: oc = t*64 + w*16 + ln
    const half8* wbase = wp + kq * 192 + w * 16 + ln;
    half8 bnx[3];
#pragma unroll
    for (int t = 0; t < 3; ++t) bnx[t] = wbase[t * 64];

#pragma unroll
    for (int s = 0; s < 36; ++s) {
        const int cc = s / 9, tap = s - cc * 9;
        const int dy = tap / 3, dx = tap - dy * 3;
        half8 bcur[3];
#pragma unroll
        for (int t = 0; t < 3; ++t) bcur[t] = bnx[t];
        if (s + 1 < 36) {
            const half8* wsrc = wbase + (size_t)(s + 1) * 768;
#pragma unroll
            for (int t = 0; t < 3; ++t) bnx[t] = wsrc[t * 64];
        }
        half8 a[4];
#pragma unroll
        for (int t = 0; t < 4; ++t)
            a[t] = lds_in[((cc * 4 + kq) * 6 + t + dy) * 18 + ln + dx];
#pragma unroll
        for (int t = 0; t < 4; ++t)
#pragma unroll
            for (int u = 0; u < 3; ++u)
                acc[t][u] = __builtin_amdgcn_mfma_f32_16x16x32_f16(a[t], bcur[u], acc[t][u], 0, 0, 0);
    }

    // epilogue: GRU gating. D layout: col(oc%16)=ln, row(x)=kq*4+reg.
    const int c = w * 16 + ln;                  // 0..63
    const float bxr = bx[c] + bh[c];
    const float bxz = bx[64 + c] + bh[64 + c];
    const float bxn = bx[128 + c];
    const float bnn = bh[128 + c];
#pragma unroll
    for (int s = 0; s < 4; ++s) {
        const int y = y0 + s;
#pragma unroll
        for (int reg = 0; reg < 4; ++reg) {
            const int x = x0 + kq * 4 + reg;
            const float xr = acc[s][0][reg] + bxr;
            const float xz = acc[s][1][reg] + bxz;
            const float xn = acc[s][2][reg] + bxn;
            const float rg = fsigmoid(xr);
            const float zg = fsigmoid(xz);
            const float n  = ftanh(xn + rg * bnn);
            const float h  = (1.f - zg) * n;
            if (out_f32)
                out_f32[((size_t)img * CH + c) * HW + y * WW + x] = h;
            else
                out_f16[((size_t)img * HW + y * WW + x) * 128 + c] = (_Float16)h;
        }
    }
}

// ---------------------------------------------------------------------------
extern "C" void kernel_launch(void* const* d_in, const int* in_sizes, int n_in,
                              void* d_out, int out_size, void* d_ws, size_t ws_size,
                              hipStream_t stream) {
    const float* feats = (const float*)d_in[0];
    const float* trans = (const float*)d_in[1];
    const float* wx    = (const float*)d_in[2];
    // d_in[3] = wh (unused: h0 = 0)
    const float* bx    = (const float*)d_in[4];
    const float* bh    = (const float*)d_in[5];
    float* out = (float*)d_out;

    char* ws = (char*)d_ws;
    half8*    wpack = (half8*)ws;                              // 442,368 B
    _Float16* B1 = (_Float16*)(ws + 442368);                   // 40 MB NHWC f16
    _Float16* B2 = (_Float16*)(ws + 442368 + (size_t)NIMG * HW * 128 * 2);

    pack_w_kernel<<<108, 256, 0, stream>>>(wx, wpack);
    to_nhwc_kernel<<<dim3(512, NIMG), 256, 0, stream>>>(feats, B1);

    dim3 wgrid(64, 4, NIMG);
    dim3 cgrid(256, 1, NIMG);      // 8 x-tiles * 32 y-tiles

    // iteration 1
    warp_mean_kernel<<<wgrid, 256, 0, stream>>>(B1, trans, B1);
    conv_gru_mfma<<<cgrid, 256, 0, stream>>>(B1, wpack, bx, bh, nullptr, B2);
    // iteration 2
    warp_mean_kernel<<<wgrid, 256, 0, stream>>>(B2, trans, B2);
    conv_gru_mfma<<<cgrid, 256, 0, stream>>>(B2, wpack, bx, bh, out, nullptr);
}